// Round 9
// baseline (551.211 us; speedup 1.0000x reference)
//
#include <hip/hip_runtime.h>
#include <math.h>

#define NROWS  16384   // B*S
#define DMODEL 1024
#define NHEAD  16
#define HDIM   64
#define SEQ    4096
#define NBATCH 4
#define NBH    64      // NBATCH*NHEAD
#define SCHUNK 16      // split-K chunks over S for kv aggregation
#define M1     1048576u

typedef __attribute__((ext_vector_type(8))) short bf16x8;
typedef __attribute__((ext_vector_type(4))) float f32x4;

#define VMCNT(N) asm volatile("s_waitcnt vmcnt(" #N ")" ::: "memory")
#define BAR() do { asm volatile("" ::: "memory"); __builtin_amdgcn_s_barrier(); \
                   asm volatile("" ::: "memory"); } while (0)

__device__ __forceinline__ unsigned short f2bf(float f) {
    unsigned u = __float_as_uint(f);
    u += 0x7FFFu + ((u >> 16) & 1u);   // round-to-nearest-even
    return (unsigned short)(u >> 16);
}
__device__ __forceinline__ float bf2f(unsigned short h) {
    return __uint_as_float((unsigned)h << 16);
}

__device__ __forceinline__ void gload16(const void* g, void* l) {
    __builtin_amdgcn_global_load_lds(
        (const __attribute__((address_space(1))) unsigned int*)g,
        (__attribute__((address_space(3))) unsigned int*)l, 16, 0, 0);
}

// ---------------------------------------------------------------------------
// split fp32 -> bf16 hi/lo pair (x: [M][1024] -> xh, xl)
// ---------------------------------------------------------------------------
__global__ __launch_bounds__(256)
void split_pair(const float* __restrict__ a, unsigned short* __restrict__ hi,
                unsigned short* __restrict__ lo, int n4)
{
    int i = blockIdx.x * 256 + threadIdx.x;
    const int stride = gridDim.x * 256;
    for (; i < n4; i += stride) {
        const float4 v = ((const float4*)a)[i];
        ushort4 H, L;
        H.x = f2bf(v.x); L.x = f2bf(v.x - bf2f(H.x));
        H.y = f2bf(v.y); L.y = f2bf(v.y - bf2f(H.y));
        H.z = f2bf(v.z); L.z = f2bf(v.z - bf2f(H.z));
        H.w = f2bf(v.w); L.w = f2bf(v.w - bf2f(H.w));
        ((ushort4*)hi)[i] = H;
        ((ushort4*)lo)[i] = L;
    }
}

// 4 weight matrices -> hi block [4096][1024] (rows: q,k,v,o) + lo block same
__global__ __launch_bounds__(256)
void split_w4(const float* __restrict__ a0, const float* __restrict__ a1,
              const float* __restrict__ a2, const float* __restrict__ a3,
              unsigned short* __restrict__ hib, unsigned short* __restrict__ lob)
{
    const int y = blockIdx.y;
    const float* src = (y == 0) ? a0 : (y == 1) ? a1 : (y == 2) ? a2 : a3;
    const int i = blockIdx.x * 256 + threadIdx.x;   // 0..262143 (= 1M/4)
    const float4 v = ((const float4*)src)[i];
    ushort4 H, L;
    H.x = f2bf(v.x); L.x = f2bf(v.x - bf2f(H.x));
    H.y = f2bf(v.y); L.y = f2bf(v.y - bf2f(H.y));
    H.z = f2bf(v.z); L.z = f2bf(v.z - bf2f(H.z));
    H.w = f2bf(v.w); L.w = f2bf(v.w - bf2f(H.w));
    const size_t o = (size_t)y * M1 + (size_t)i * 4;
    *(ushort4*)&hib[o] = H;
    *(ushort4*)&lob[o] = L;
}

// ---------------------------------------------------------------------------
// Split-bf16 GEMM (NT), 3-buffer counted pipeline (T3+T4+T5):
// C = A@W^T + bias, 3 MFMA passes (hh+hl+lh), separate hi/lo arrays (1x fetch).
// Tile 256M x 128N, BK=32 (32 K-tiles), 8 waves 4Mx2N (wave = 64x64).
// LDS: 3 buffers x 48KB = 144KB; buffer = [Ah 16K | Al 16K | Bh 8K | Bl 8K].
// 6 gload16/thread/tile, prefetch depth 2 -> steady s_waitcnt vmcnt(6) at the
// single per-tile barrier (never drains in main loop). 4 phases per tile:
// {2 ds_read A (+8 B in ph0) | 2 stage loads | setprio 12 MFMA}.
// Transposed-cell chunks (16r x 32k as [kslot][row]) via pre-permuted global
// source, LDS dest linear -> 0 bank conflicts (r8-verified).
// MODE: 0 = plain (o-proj), 1 = elu+1 (q), 2 = fused k|v (k: elu -> C0,
// v: plain -> C1); W rows = wrow0 + nb*128 into the big [4096][1024] block.
// ---------------------------------------------------------------------------
template<int MODE>
__global__ __launch_bounds__(512)
void gemm_t3(const unsigned short* __restrict__ Ah, const unsigned short* __restrict__ Al,
             const unsigned short* __restrict__ WhB, const unsigned short* __restrict__ WlB,
             const float* __restrict__ bias0, const float* __restrict__ bias1,
             float* __restrict__ C0, float* __restrict__ C1, int nbs, int wrow0)
{
    __shared__ unsigned short lds[73728];   // 3 x 24576 ushorts (48KB each)
    const int t    = threadIdx.x;
    const int lane = t & 63;
    const int wv   = t >> 6;        // wave 0..7
    const int wr   = wv >> 1;       // M quarter 0..3 (64 rows)
    const int wcn  = wv & 1;        // N half    0..1 (64 cols)

    // XCD swizzle (bijective; gridDim.x divisible by 8)
    const int bid  = blockIdx.x;
    const int swz  = (bid & 7) * ((int)gridDim.x >> 3) + (bid >> 3);
    const int NBm  = (1 << nbs) - 1;
    const int mb   = swz >> nbs;
    const int nb   = swz & NBm;
    const int am0  = mb * 256;              // A panel row base
    const int bn0g = wrow0 + nb * 128;      // W row base in the big block

    const int fr   = lane & 15;                          // frag row
    const int j0   = lane >> 4;                          // frag k-slot 0..3
    const unsigned fro = (unsigned)((j0 * 16 + fr) * 8); // within-chunk frag offset
    const int srcr = lane & 15;                          // staging src row-in-chunk
    const int srcc = (lane >> 4) * 8;                    // staging src k-offset

    f32x4 acc[4][4];
#pragma unroll
    for (int i = 0; i < 4; ++i)
#pragma unroll
        for (int j = 0; j < 4; ++j)
#pragma unroll
            for (int e = 0; e < 4; ++e) acc[i][j][e] = 0.f;

    // full-tile stage (prologue): 6 gload16 in canonical order A.c0, A.c1, B
    auto stage_full = [&](int kt, unsigned wb) {
#pragma unroll
        for (int c = 0; c < 2; ++c) {
            const int ch = wv * 2 + c;
            const size_t ga = (size_t)(am0 + ch * 16 + srcr) * DMODEL + kt * 32 + srcc;
            gload16(Ah + ga, (unsigned short*)&lds[wb + (unsigned)ch * 512u]);
            gload16(Al + ga, (unsigned short*)&lds[wb + 8192u + (unsigned)ch * 512u]);
        }
        const size_t gb = (size_t)(bn0g + wv * 16 + srcr) * DMODEL + kt * 32 + srcc;
        gload16(WhB + gb, (unsigned short*)&lds[wb + 16384u + (unsigned)wv * 512u]);
        gload16(WlB + gb, (unsigned short*)&lds[wb + 20480u + (unsigned)wv * 512u]);
    };

    // compute tile from rd; optionally stage tile k2 into wb (same 6 loads,
    // spread 2/2/2 over phases 0/1/2)
    auto phases = [&](unsigned rd, unsigned wb, int k2, bool doStage) {
        bf16x8 bh[4], bl[4];
#pragma unroll
        for (int j = 0; j < 4; ++j) {
            const unsigned ch = (unsigned)(wcn * 4 + j) * 512u;
            bh[j] = *(const bf16x8*)&lds[rd + 16384u + ch + fro];
            bl[j] = *(const bf16x8*)&lds[rd + 20480u + ch + fro];
        }
#pragma unroll
        for (int p = 0; p < 4; ++p) {
            const unsigned ch = (unsigned)(wr * 4 + p) * 512u;
            const bf16x8 a_h = *(const bf16x8*)&lds[rd + ch + fro];
            const bf16x8 a_l = *(const bf16x8*)&lds[rd + 8192u + ch + fro];
            if (doStage) {
                if (p < 2) {           // A chunk c=p
                    const int cch = wv * 2 + p;
                    const size_t ga = (size_t)(am0 + cch * 16 + srcr) * DMODEL + k2 * 32 + srcc;
                    gload16(Ah + ga, (unsigned short*)&lds[wb + (unsigned)cch * 512u]);
                    gload16(Al + ga, (unsigned short*)&lds[wb + 8192u + (unsigned)cch * 512u]);
                } else if (p == 2) {   // B chunk
                    const size_t gb = (size_t)(bn0g + wv * 16 + srcr) * DMODEL + k2 * 32 + srcc;
                    gload16(WhB + gb, (unsigned short*)&lds[wb + 16384u + (unsigned)wv * 512u]);
                    gload16(WlB + gb, (unsigned short*)&lds[wb + 20480u + (unsigned)wv * 512u]);
                }
            }
            __builtin_amdgcn_s_setprio(1);
#pragma unroll
            for (int j = 0; j < 4; ++j) {
                acc[p][j] = __builtin_amdgcn_mfma_f32_16x16x32_bf16(a_h, bh[j], acc[p][j], 0, 0, 0);
                acc[p][j] = __builtin_amdgcn_mfma_f32_16x16x32_bf16(a_h, bl[j], acc[p][j], 0, 0, 0);
                acc[p][j] = __builtin_amdgcn_mfma_f32_16x16x32_bf16(a_l, bh[j], acc[p][j], 0, 0, 0);
            }
            __builtin_amdgcn_s_setprio(0);
        }
    };

    // prologue: 2 tiles in flight (12 loads/thread)
    stage_full(0, 0u);
    stage_full(1, 24576u);

    // steady state: at each tile barrier, outstanding = 12; vmcnt(6) retires
    // the oldest tile's 6. Buffers rotate 0,1,2. 30 = 3*10 main iterations.
    for (int kt = 0; kt < 30; kt += 3) {
        VMCNT(6); BAR(); phases(0u,     49152u, kt + 2, true);
        VMCNT(6); BAR(); phases(24576u, 0u,     kt + 3, true);
        VMCNT(6); BAR(); phases(49152u, 24576u, kt + 4, true);
    }
    VMCNT(6); BAR(); phases(0u,     0u, 0, false);   // kt=30 (buf 30%3=0)
    VMCNT(0); BAR(); phases(24576u, 0u, 0, false);   // kt=31 (buf 1), drain

    // epilogue: C/D layout col=lane&15, row=(lane>>4)*4+reg
    const bool elu = (MODE == 1) || (MODE == 2 && nb < 8);
    float* Cm = C0;
    const float* bm = bias0;
    int coff = 0;
    if (MODE == 2 && nb >= 8) { Cm = C1; bm = bias1; coff = 1024; }
    const int crow0 = am0 + wr * 64 + (lane >> 4) * 4;
    const int ccol0 = nb * 128 + wcn * 64 + fr - coff;
#pragma unroll
    for (int j = 0; j < 4; ++j) {
        const int col = ccol0 + j * 16;
        const float bv = bm[col];
#pragma unroll
        for (int i = 0; i < 4; ++i) {
            const int row = crow0 + i * 16;
#pragma unroll
            for (int r = 0; r < 4; ++r) {
                float v = acc[i][j][r] + bv;
                if (elu) v = (v > 0.f) ? (v + 1.f) : __expf(v);  // elu(v)+1
                Cm[(size_t)(row + r) * DMODEL + col] = v;
            }
        }
    }
}

// ---------------------------------------------------------------------------
// kv partials: for (b,h,sc): kvp[d][e] = sum_{s in chunk} k[s,d]*v[s,e],
// ksp[d] = sum k[s,d]. Deterministic split-K, no atomics.
// ---------------------------------------------------------------------------
__global__ __launch_bounds__(512)
void kv_partial(const float* __restrict__ k, const float* __restrict__ v,
                float* __restrict__ kvp, float* __restrict__ ksp)
{
    __shared__ float Ks[32][64];
    __shared__ float Vs[32][64];
    const int t  = threadIdx.x;
    const int bh = blockIdx.x;
    const int b  = bh >> 4;
    const int h  = bh & 15;
    const int sc = blockIdx.y;
    const int d  = t & 63;
    const int e0 = (t >> 6) * 8;

    float acc[8];
#pragma unroll
    for (int j = 0; j < 8; ++j) acc[j] = 0.f;
    float ks = 0.f;

    const size_t rowbase = (size_t)b * SEQ;
    const int sbeg = sc * (SEQ / SCHUNK);       // 256 rows per chunk
    const int send = sbeg + (SEQ / SCHUNK);
    const int lrow = t >> 4;                    // staging: 0..31
    const int lc4  = (t & 15) * 4;

    for (int s0 = sbeg; s0 < send; s0 += 32) {
        const size_t g = (rowbase + s0 + lrow) * DMODEL + h * HDIM + lc4;
        *(float4*)&Ks[lrow][lc4] = *(const float4*)&k[g];
        *(float4*)&Vs[lrow][lc4] = *(const float4*)&v[g];
        __syncthreads();
#pragma unroll 8
        for (int sp = 0; sp < 32; ++sp) {
            const float kd = Ks[sp][d];
            if (t < 64) ks += Ks[sp][t];        // wave 0 only (wave-uniform branch)
            const float4 v0 = *(const float4*)&Vs[sp][e0 + 0];
            const float4 v1 = *(const float4*)&Vs[sp][e0 + 4];
            acc[0] = fmaf(kd, v0.x, acc[0]);  acc[1] = fmaf(kd, v0.y, acc[1]);
            acc[2] = fmaf(kd, v0.z, acc[2]);  acc[3] = fmaf(kd, v0.w, acc[3]);
            acc[4] = fmaf(kd, v1.x, acc[4]);  acc[5] = fmaf(kd, v1.y, acc[5]);
            acc[6] = fmaf(kd, v1.z, acc[6]);  acc[7] = fmaf(kd, v1.w, acc[7]);
        }
        __syncthreads();
    }

    const size_t base = ((size_t)sc * NBH + bh) * HDIM;
    float4 o0; o0.x = acc[0]; o0.y = acc[1]; o0.z = acc[2]; o0.w = acc[3];
    float4 o1; o1.x = acc[4]; o1.y = acc[5]; o1.z = acc[6]; o1.w = acc[7];
    *(float4*)&kvp[(base + d) * HDIM + e0 + 0] = o0;
    *(float4*)&kvp[(base + d) * HDIM + e0 + 4] = o1;
    if (t < 64) ksp[base + t] = ks;
}

__global__ __launch_bounds__(256)
void kv_reduce(const float* __restrict__ kvp, const float* __restrict__ ksp,
               float* __restrict__ kv, float* __restrict__ ksum)
{
    const int i = blockIdx.x * 256 + threadIdx.x;
    const int NKV = NBH * HDIM * HDIM;
    if (i < NKV) {
        float s = 0.f;
#pragma unroll
        for (int c = 0; c < SCHUNK; ++c) s += kvp[(size_t)c * NKV + i];
        kv[i] = s;
    }
    if (i < NBH * HDIM) {
        float s = 0.f;
#pragma unroll
        for (int c = 0; c < SCHUNK; ++c) s += ksp[(size_t)c * NBH * HDIM + i];
        ksum[i] = s;
    }
}

// ---------------------------------------------------------------------------
// att[s,e] = (sum_d q[s,d]*kv[d,e]) / (sum_d q[s,d]*ksum[d] + 1e-6),
// written directly as bf16 hi/lo (fused split for the final GEMM's A-operand).
// ---------------------------------------------------------------------------
__global__ __launch_bounds__(256)
void qkv_norm(const float* __restrict__ q, const float* __restrict__ kv,
              const float* __restrict__ ksum,
              unsigned short* __restrict__ ah, unsigned short* __restrict__ al)
{
    __shared__ float Qs[64][68];
    __shared__ float KVs[64][64];
    __shared__ float kss[64];
    const int t  = threadIdx.x;
    const int s0 = blockIdx.x * 64;
    const int b  = blockIdx.y;
    const int h  = blockIdx.z;
    const int bh = b * NHEAD + h;

#pragma unroll
    for (int i = 0; i < 4; ++i) {
        const int idx = i * 256 + t;
        const int row = idx >> 4;
        const int c4  = (idx & 15) * 4;
        const float4 vq = *(const float4*)&q[((size_t)b * SEQ + s0 + row) * DMODEL + h * HDIM + c4];
        *(float4*)&Qs[row][c4] = vq;
        *(float4*)&((float*)KVs)[idx * 4] = *(const float4*)&kv[(size_t)bh * HDIM * HDIM + idx * 4];
    }
    if (t < 64) kss[t] = ksum[(size_t)bh * HDIM + t];
    __syncthreads();

    const int r  = t >> 2;
    const int e0 = (t & 3) * 16;
    float out[16];
#pragma unroll
    for (int j = 0; j < 16; ++j) out[j] = 0.f;
    float nrm = 0.f;

#pragma unroll 8
    for (int d = 0; d < 64; ++d) {
        const float qd = Qs[r][d];
        nrm = fmaf(qd, kss[d], nrm);
        const float4 k0 = *(const float4*)&KVs[d][e0 + 0];
        const float4 k1 = *(const float4*)&KVs[d][e0 + 4];
        const float4 k2 = *(const float4*)&KVs[d][e0 + 8];
        const float4 k3 = *(const float4*)&KVs[d][e0 + 12];
        out[0]  = fmaf(qd, k0.x, out[0]);  out[1]  = fmaf(qd, k0.y, out[1]);
        out[2]  = fmaf(qd, k0.z, out[2]);  out[3]  = fmaf(qd, k0.w, out[3]);
        out[4]  = fmaf(qd, k1.x, out[4]);  out[5]  = fmaf(qd, k1.y, out[5]);
        out[6]  = fmaf(qd, k1.z, out[6]);  out[7]  = fmaf(qd, k1.w, out[7]);
        out[8]  = fmaf(qd, k2.x, out[8]);  out[9]  = fmaf(qd, k2.y, out[9]);
        out[10] = fmaf(qd, k2.z, out[10]); out[11] = fmaf(qd, k2.w, out[11]);
        out[12] = fmaf(qd, k3.x, out[12]); out[13] = fmaf(qd, k3.y, out[13]);
        out[14] = fmaf(qd, k3.z, out[14]); out[15] = fmaf(qd, k3.w, out[15]);
    }

    const float inv = 1.f / (nrm + 1e-6f);
    const size_t gbase = ((size_t)b * SEQ + s0 + r) * DMODEL + h * HDIM + e0;
#pragma unroll
    for (int g4 = 0; g4 < 4; ++g4) {
        ushort4 H, L;
        const float v0 = out[g4*4+0] * inv;
        const float v1 = out[g4*4+1] * inv;
        const float v2 = out[g4*4+2] * inv;
        const float v3 = out[g4*4+3] * inv;
        H.x = f2bf(v0); L.x = f2bf(v0 - bf2f(H.x));
        H.y = f2bf(v1); L.y = f2bf(v1 - bf2f(H.y));
        H.z = f2bf(v2); L.z = f2bf(v2 - bf2f(H.z));
        H.w = f2bf(v3); L.w = f2bf(v3 - bf2f(H.w));
        *(ushort4*)&ah[gbase + g4 * 4] = H;
        *(ushort4*)&al[gbase + g4 * 4] = L;
    }
}

// ---------------------------------------------------------------------------
extern "C" void kernel_launch(void* const* d_in, const int* in_sizes, int n_in,
                              void* d_out, int out_size, void* d_ws, size_t ws_size,
                              hipStream_t stream)
{
    const float* x  = (const float*)d_in[0];
    const float* Wq = (const float*)d_in[1];
    const float* bq = (const float*)d_in[2];
    const float* Wk = (const float*)d_in[3];
    const float* bk = (const float*)d_in[4];
    const float* Wv = (const float*)d_in[5];
    const float* bv = (const float*)d_in[6];
    const float* Wo = (const float*)d_in[7];
    const float* bo = (const float*)d_in[8];

    // workspace layout (~161 MB):
    unsigned short* xh  = (unsigned short*)d_ws;                   // [16384][1024] bf16 hi (x, then att)
    unsigned short* xl  = xh + (size_t)NROWS * DMODEL;             // lo
    unsigned short* hib = xl + (size_t)NROWS * DMODEL;             // W hi block [4096][1024] (q,k,v,o)
    unsigned short* lob = hib + 4u * M1;                           // W lo block [4096][1024]
    float* buf0 = (float*)(lob + 4u * M1);                         // k, then q (fp32)
    float* kv   = buf0 + (size_t)NROWS * DMODEL;                   // [NBH][64][64]
    float* ksum = kv + NBH * HDIM * HDIM;                          // [NBH][64]
    float* kvp  = ksum + NBH * HDIM;                               // [SCHUNK][NBH][64][64]
    float* ksp  = kvp + (size_t)SCHUNK * NBH * HDIM * HDIM;        // [SCHUNK][NBH][64]
    float* vbuf = (float*)d_out;                                   // v lives in d_out (dead before final GEMM)

    const int n4x = NROWS * DMODEL / 4;

    // convert weights + x to bf16 hi/lo
    split_w4<<<dim3(1024, 4), 256, 0, stream>>>(Wq, Wk, Wv, Wo, hib, lob);
    split_pair<<<4096, 256, 0, stream>>>(x, xh, xl, n4x);
    // fused: k = elu(x@Wk^T + bk)+1 -> buf0 ; v = x@Wv^T + bv -> vbuf
    gemm_t3<2><<<1024, 512, 0, stream>>>(xh, xl, hib, lob, bk, bv, buf0, vbuf, 4, 1024);
    // kv, ksum (deterministic split-K + reduce)
    kv_partial<<<dim3(NBH, SCHUNK), 512, 0, stream>>>(buf0, vbuf, kvp, ksp);
    kv_reduce<<<1024, 256, 0, stream>>>(kvp, ksp, kv, ksum);
    // q = elu(x@Wq^T + bq)+1   (overwrites k)
    gemm_t3<1><<<512, 512, 0, stream>>>(xh, xl, hib, lob, bq, nullptr, buf0, nullptr, 3, 0);
    // att = (q@kv)/(q@ksum + 1e-6), fused bf16 hi/lo split (x split is dead)
    qkv_norm<<<dim3(SEQ / 64, NBATCH, NHEAD), 256, 0, stream>>>(buf0, kv, ksum, xh, xl);
    // out = att@Wo^T + bo  (overwrites v in d_out)
    gemm_t3<0><<<512, 512, 0, stream>>>(xh, xl, hib, lob, bo, nullptr, (float*)d_out, nullptr, 3, 3072);
}

// Round 10
// 493.523 us; speedup vs baseline: 1.1169x; 1.1169x over previous
//
#include <hip/hip_runtime.h>
#include <math.h>

#define NROWS  16384   // B*S
#define DMODEL 1024
#define NHEAD  16
#define HDIM   64
#define SEQ    4096
#define NBATCH 4
#define NBH    64      // NBATCH*NHEAD
#define SCHUNK 16      // split-K chunks over S for kv aggregation
#define M1     1048576u

typedef __attribute__((ext_vector_type(8))) short bf16x8;
typedef __attribute__((ext_vector_type(4))) float f32x4;

#define VMCNT(N) asm volatile("s_waitcnt vmcnt(" #N ")" ::: "memory")
#define BAR() do { asm volatile("" ::: "memory"); __builtin_amdgcn_s_barrier(); \
                   asm volatile("" ::: "memory"); } while (0)

__device__ __forceinline__ unsigned short f2bf(float f) {
    unsigned u = __float_as_uint(f);
    u += 0x7FFFu + ((u >> 16) & 1u);   // round-to-nearest-even
    return (unsigned short)(u >> 16);
}
__device__ __forceinline__ float bf2f(unsigned short h) {
    return __uint_as_float((unsigned)h << 16);
}

__device__ __forceinline__ void gload16(const void* g, void* l) {
    __builtin_amdgcn_global_load_lds(
        (const __attribute__((address_space(1))) unsigned int*)g,
        (__attribute__((address_space(3))) unsigned int*)l, 16, 0, 0);
}

// ---------------------------------------------------------------------------
// split fp32 -> bf16 hi/lo pair (grid-stride, float4/ushort4 vectorized)
// ---------------------------------------------------------------------------
__global__ __launch_bounds__(256)
void split_pair(const float* __restrict__ a, unsigned short* __restrict__ hi,
                unsigned short* __restrict__ lo, int n4)
{
    int i = blockIdx.x * 256 + threadIdx.x;
    const int stride = gridDim.x * 256;
    for (; i < n4; i += stride) {
        const float4 v = ((const float4*)a)[i];
        ushort4 H, L;
        H.x = f2bf(v.x); L.x = f2bf(v.x - bf2f(H.x));
        H.y = f2bf(v.y); L.y = f2bf(v.y - bf2f(H.y));
        H.z = f2bf(v.z); L.z = f2bf(v.z - bf2f(H.z));
        H.w = f2bf(v.w); L.w = f2bf(v.w - bf2f(H.w));
        ((ushort4*)hi)[i] = H;
        ((ushort4*)lo)[i] = L;
    }
}

// all 4 weight matrices in one launch: dst = [Wq_h,Wq_l,Wk_h,Wk_l,Wv_h,Wv_l,Wo_h,Wo_l]
__global__ __launch_bounds__(256)
void split_w4(const float* __restrict__ a0, const float* __restrict__ a1,
              const float* __restrict__ a2, const float* __restrict__ a3,
              unsigned short* __restrict__ dst)
{
    const int y = blockIdx.y;
    const float* src = (y == 0) ? a0 : (y == 1) ? a1 : (y == 2) ? a2 : a3;
    unsigned short* hi = dst + (size_t)y * 2u * M1;
    unsigned short* lo = hi + M1;
    const int i = blockIdx.x * 256 + threadIdx.x;   // 0..262143 (= 1M/4)
    const float4 v = ((const float4*)src)[i];
    ushort4 H, L;
    H.x = f2bf(v.x); L.x = f2bf(v.x - bf2f(H.x));
    H.y = f2bf(v.y); L.y = f2bf(v.y - bf2f(H.y));
    H.z = f2bf(v.z); L.z = f2bf(v.z - bf2f(H.z));
    H.w = f2bf(v.w); L.w = f2bf(v.w - bf2f(H.w));
    ((ushort4*)hi)[i] = H;
    ((ushort4*)lo)[i] = L;
}

// ---------------------------------------------------------------------------
// Split-bf16 GEMM (NT) = r8 structure + counted-vmcnt staging stream.
// C = A@W^T + bias, optional elu+1. 256x256 tile, BK=32 (32 tiles), 8 waves
// (2Mx4N), per-wave 128x64, 3 MFMA passes (hh+hl+lh). LDS 2 x 64KiB dbuf,
// transposed-cell chunks (0 bank conflicts, r8-verified).
// Stage stream (units of 2 gload16/thread, FIFO): per tile [Wh,Wl,Ah,Al];
// unit issued 6 phases before first use (ph0 of kt stages Ah(kt+1); ph1:
// Al(kt+1); ph2: Wh(kt+2); ph3: Wl(kt+2)). Tile entry: s_waitcnt vmcnt(4)
// (newest 4 loads = Wh/Wl of kt+1 stay in flight) + barrier -> global
// guarantee tile kt's 4 units landed. vmcnt(0) only at the final tile.
// Clobber-safety: B-units are read only in ph0 (reg-cached), so the kt+2
// W-overwrites issued in ph2/ph3 of kt are sealed by >=2 barriers; A-units'
// kt+2 overwrites are issued in ph0/ph1 of kt+1, after the tile barrier
// that seals kt's ph3 A-reads. 8 barriers/tile, same cadence as r8.
// ---------------------------------------------------------------------------
template<int ELU>
__global__ __launch_bounds__(512)
void gemm_cp(const unsigned short* __restrict__ Ah, const unsigned short* __restrict__ Al,
             const unsigned short* __restrict__ Wh, const unsigned short* __restrict__ Wl,
             const float* __restrict__ bias, float* __restrict__ C)
{
    __shared__ unsigned short lds[2 * 32768];   // 2 x 64 KiB buffers
    const int t    = threadIdx.x;
    const int lane = t & 63;
    const int wv   = t >> 6;        // wave 0..7
    const int wr   = wv >> 2;       // M half   0..1
    const int wcn  = wv & 3;        // N quarter 0..3

    // XCD swizzle (bijective, 256 blocks): 8 m-panels x 4 n per XCD
    const int bid  = blockIdx.x;
    const int swz  = ((bid & 7) << 5) | (bid >> 3);
    const int am0  = (swz >> 2) * 256;     // A panel row base
    const int bn0  = (swz & 3) * 256;      // W panel row base (= C col base)

    const int fr   = lane & 15;            // frag row
    const int j0   = lane >> 4;            // frag k-slot 0..3
    const unsigned fro = (unsigned)((j0 * 16 + fr) * 8);  // within-chunk frag offset
    const int srcr = lane & 15;            // staging source: row within chunk
    const int srcc = (lane >> 4) * 8;      // staging source: k offset (8 bf16 = 16B)

    f32x4 acc[8][4];
#pragma unroll
    for (int i = 0; i < 8; ++i)
#pragma unroll
        for (int j = 0; j < 4; ++j)
#pragma unroll
            for (int e = 0; e < 4; ++e) acc[i][j][e] = 0.f;

    // stage one unit (op: 0=Ah 1=Al 2=Wh 3=Wl) of K-tile kt (2 gload16/thread).
    // LDS region: buffer (kt&1) + op*8192 ushorts. Transposed-cell chunks.
    auto stage_op = [&](int kt, int op) {
        if (kt >= 32) return;
        const unsigned short* gs = (op == 0) ? Ah : (op == 1) ? Al : (op == 2) ? Wh : Wl;
        const int rbase = (op < 2) ? am0 : bn0;
        const int k0 = kt * 32;
        const unsigned wb = ((unsigned)kt & 1u) * 32768u + (unsigned)op * 8192u;
#pragma unroll
        for (int c = 0; c < 2; ++c) {
            const int grow = rbase + c * 128 + wv * 16 + srcr;
            gload16(gs + (size_t)grow * DMODEL + k0 + srcc,
                    (unsigned short*)&lds[wb + (unsigned)(c * 8 + wv) * 512u]);
        }
    };

    // prologue, FIFO stream order: Wh(0),Wl(0),Ah(0),Al(0),Wh(1),Wl(1)
    stage_op(0, 2); stage_op(0, 3); stage_op(0, 0); stage_op(0, 1);
    stage_op(1, 2); stage_op(1, 3);

    for (int ks = 0; ks < 32; ++ks) {
        const unsigned rb = ((unsigned)ks & 1u) * 32768u;
        // tile entry: counted wait (all but newest 2 units landed), then barrier
        if (ks < 31) { VMCNT(4); } else { VMCNT(0); }
        BAR();

        bf16x8 bh[4], bl[4];
#pragma unroll
        for (int ph = 0; ph < 4; ++ph) {
            if (ph == 0) {
#pragma unroll
                for (int j = 0; j < 4; ++j) {
                    const unsigned ch = (unsigned)(wcn * 4 + j) * 512u;   // B chunk
                    bh[j] = *(const bf16x8*)&lds[rb + 16384u + ch + fro];
                    bl[j] = *(const bf16x8*)&lds[rb + 24576u + ch + fro];
                }
            }
            bf16x8 a_h[2], a_l[2];
#pragma unroll
            for (int i2 = 0; i2 < 2; ++i2) {
                const unsigned ch = (unsigned)(wr * 8 + ph * 2 + i2) * 512u;  // A chunk
                a_h[i2] = *(const bf16x8*)&lds[rb + ch + fro];
                a_l[i2] = *(const bf16x8*)&lds[rb + 8192u + ch + fro];
            }
            // stage stream, +6-unit stagger (see header comment)
            if (ph == 0)      stage_op(ks + 1, 0);
            else if (ph == 1) stage_op(ks + 1, 1);
            else if (ph == 2) stage_op(ks + 2, 2);
            else              stage_op(ks + 2, 3);
            __builtin_amdgcn_s_barrier();
            __builtin_amdgcn_s_setprio(1);
#pragma unroll
            for (int i2 = 0; i2 < 2; ++i2)
#pragma unroll
                for (int j = 0; j < 4; ++j) {
                    acc[ph * 2 + i2][j] = __builtin_amdgcn_mfma_f32_16x16x32_bf16(a_h[i2], bh[j], acc[ph * 2 + i2][j], 0, 0, 0);
                    acc[ph * 2 + i2][j] = __builtin_amdgcn_mfma_f32_16x16x32_bf16(a_h[i2], bl[j], acc[ph * 2 + i2][j], 0, 0, 0);
                    acc[ph * 2 + i2][j] = __builtin_amdgcn_mfma_f32_16x16x32_bf16(a_l[i2], bh[j], acc[ph * 2 + i2][j], 0, 0, 0);
                }
            __builtin_amdgcn_s_setprio(0);
            if (ph < 3) __builtin_amdgcn_s_barrier();
        }
    }

    // epilogue: C/D layout col=lane&15, row=(lane>>4)*4+reg
    const int crow0 = am0 + wr * 128 + (lane >> 4) * 4;
    const int ccol0 = bn0 + wcn * 64 + fr;
#pragma unroll
    for (int j = 0; j < 4; ++j) {
        const int col = ccol0 + j * 16;
        const float bv = bias[col];
#pragma unroll
        for (int i = 0; i < 8; ++i) {
            const int row = crow0 + i * 16;
#pragma unroll
            for (int r = 0; r < 4; ++r) {
                float v = acc[i][j][r] + bv;
                if (ELU) v = (v > 0.f) ? (v + 1.f) : __expf(v);  // elu(v)+1
                C[(size_t)(row + r) * DMODEL + col] = v;
            }
        }
    }
}

// ---------------------------------------------------------------------------
// kv partials: for (b,h,sc): kvp[d][e] = sum_{s in chunk} k[s,d]*v[s,e],
// ksp[d] = sum k[s,d]. Deterministic split-K, no atomics.
// ---------------------------------------------------------------------------
__global__ __launch_bounds__(512)
void kv_partial(const float* __restrict__ k, const float* __restrict__ v,
                float* __restrict__ kvp, float* __restrict__ ksp)
{
    __shared__ float Ks[32][64];
    __shared__ float Vs[32][64];
    const int t  = threadIdx.x;
    const int bh = blockIdx.x;
    const int b  = bh >> 4;
    const int h  = bh & 15;
    const int sc = blockIdx.y;
    const int d  = t & 63;
    const int e0 = (t >> 6) * 8;

    float acc[8];
#pragma unroll
    for (int j = 0; j < 8; ++j) acc[j] = 0.f;
    float ks = 0.f;

    const size_t rowbase = (size_t)b * SEQ;
    const int sbeg = sc * (SEQ / SCHUNK);       // 256 rows per chunk
    const int send = sbeg + (SEQ / SCHUNK);
    const int lrow = t >> 4;                    // staging: 0..31
    const int lc4  = (t & 15) * 4;

    for (int s0 = sbeg; s0 < send; s0 += 32) {
        const size_t g = (rowbase + s0 + lrow) * DMODEL + h * HDIM + lc4;
        *(float4*)&Ks[lrow][lc4] = *(const float4*)&k[g];
        *(float4*)&Vs[lrow][lc4] = *(const float4*)&v[g];
        __syncthreads();
#pragma unroll 8
        for (int sp = 0; sp < 32; ++sp) {
            const float kd = Ks[sp][d];
            if (t < 64) ks += Ks[sp][t];        // wave 0 only (wave-uniform branch)
            const float4 v0 = *(const float4*)&Vs[sp][e0 + 0];
            const float4 v1 = *(const float4*)&Vs[sp][e0 + 4];
            acc[0] = fmaf(kd, v0.x, acc[0]);  acc[1] = fmaf(kd, v0.y, acc[1]);
            acc[2] = fmaf(kd, v0.z, acc[2]);  acc[3] = fmaf(kd, v0.w, acc[3]);
            acc[4] = fmaf(kd, v1.x, acc[4]);  acc[5] = fmaf(kd, v1.y, acc[5]);
            acc[6] = fmaf(kd, v1.z, acc[6]);  acc[7] = fmaf(kd, v1.w, acc[7]);
        }
        __syncthreads();
    }

    const size_t base = ((size_t)sc * NBH + bh) * HDIM;
    float4 o0; o0.x = acc[0]; o0.y = acc[1]; o0.z = acc[2]; o0.w = acc[3];
    float4 o1; o1.x = acc[4]; o1.y = acc[5]; o1.z = acc[6]; o1.w = acc[7];
    *(float4*)&kvp[(base + d) * HDIM + e0 + 0] = o0;
    *(float4*)&kvp[(base + d) * HDIM + e0 + 4] = o1;
    if (t < 64) ksp[base + t] = ks;
}

__global__ __launch_bounds__(256)
void kv_reduce(const float* __restrict__ kvp, const float* __restrict__ ksp,
               float* __restrict__ kv, float* __restrict__ ksum)
{
    const int i = blockIdx.x * 256 + threadIdx.x;
    const int NKV = NBH * HDIM * HDIM;
    if (i < NKV) {
        float s = 0.f;
#pragma unroll
        for (int c = 0; c < SCHUNK; ++c) s += kvp[(size_t)c * NKV + i];
        kv[i] = s;
    }
    if (i < NBH * HDIM) {
        float s = 0.f;
#pragma unroll
        for (int c = 0; c < SCHUNK; ++c) s += ksp[(size_t)c * NBH * HDIM + i];
        ksum[i] = s;
    }
}

// ---------------------------------------------------------------------------
// att[s,e] = (sum_d q[s,d]*kv[d,e]) / (sum_d q[s,d]*ksum[d] + 1e-6),
// written directly as bf16 hi/lo (fused split for the final GEMM's A-operand).
// ---------------------------------------------------------------------------
__global__ __launch_bounds__(256)
void qkv_norm(const float* __restrict__ q, const float* __restrict__ kv,
              const float* __restrict__ ksum,
              unsigned short* __restrict__ ah, unsigned short* __restrict__ al)
{
    __shared__ float Qs[64][68];
    __shared__ float KVs[64][64];
    __shared__ float kss[64];
    const int t  = threadIdx.x;
    const int s0 = blockIdx.x * 64;
    const int b  = blockIdx.y;
    const int h  = blockIdx.z;
    const int bh = b * NHEAD + h;

#pragma unroll
    for (int i = 0; i < 4; ++i) {
        const int idx = i * 256 + t;
        const int row = idx >> 4;
        const int c4  = (idx & 15) * 4;
        const float4 vq = *(const float4*)&q[((size_t)b * SEQ + s0 + row) * DMODEL + h * HDIM + c4];
        *(float4*)&Qs[row][c4] = vq;
        *(float4*)&((float*)KVs)[idx * 4] = *(const float4*)&kv[(size_t)bh * HDIM * HDIM + idx * 4];
    }
    if (t < 64) kss[t] = ksum[(size_t)bh * HDIM + t];
    __syncthreads();

    const int r  = t >> 2;
    const int e0 = (t & 3) * 16;
    float out[16];
#pragma unroll
    for (int j = 0; j < 16; ++j) out[j] = 0.f;
    float nrm = 0.f;

#pragma unroll 8
    for (int d = 0; d < 64; ++d) {
        const float qd = Qs[r][d];
        nrm = fmaf(qd, kss[d], nrm);
        const float4 k0 = *(const float4*)&KVs[d][e0 + 0];
        const float4 k1 = *(const float4*)&KVs[d][e0 + 4];
        const float4 k2 = *(const float4*)&KVs[d][e0 + 8];
        const float4 k3 = *(const float4*)&KVs[d][e0 + 12];
        out[0]  = fmaf(qd, k0.x, out[0]);  out[1]  = fmaf(qd, k0.y, out[1]);
        out[2]  = fmaf(qd, k0.z, out[2]);  out[3]  = fmaf(qd, k0.w, out[3]);
        out[4]  = fmaf(qd, k1.x, out[4]);  out[5]  = fmaf(qd, k1.y, out[5]);
        out[6]  = fmaf(qd, k1.z, out[6]);  out[7]  = fmaf(qd, k1.w, out[7]);
        out[8]  = fmaf(qd, k2.x, out[8]);  out[9]  = fmaf(qd, k2.y, out[9]);
        out[10] = fmaf(qd, k2.z, out[10]); out[11] = fmaf(qd, k2.w, out[11]);
        out[12] = fmaf(qd, k3.x, out[12]); out[13] = fmaf(qd, k3.y, out[13]);
        out[14] = fmaf(qd, k3.z, out[14]); out[15] = fmaf(qd, k3.w, out[15]);
    }

    const float inv = 1.f / (nrm + 1e-6f);
    const size_t gbase = ((size_t)b * SEQ + s0 + r) * DMODEL + h * HDIM + e0;
#pragma unroll
    for (int g4 = 0; g4 < 4; ++g4) {
        ushort4 H, L;
        const float v0 = out[g4*4+0] * inv;
        const float v1 = out[g4*4+1] * inv;
        const float v2 = out[g4*4+2] * inv;
        const float v3 = out[g4*4+3] * inv;
        H.x = f2bf(v0); L.x = f2bf(v0 - bf2f(H.x));
        H.y = f2bf(v1); L.y = f2bf(v1 - bf2f(H.y));
        H.z = f2bf(v2); L.z = f2bf(v2 - bf2f(H.z));
        H.w = f2bf(v3); L.w = f2bf(v3 - bf2f(H.w));
        *(ushort4*)&ah[gbase + g4 * 4] = H;
        *(ushort4*)&al[gbase + g4 * 4] = L;
    }
}

// ---------------------------------------------------------------------------
extern "C" void kernel_launch(void* const* d_in, const int* in_sizes, int n_in,
                              void* d_out, int out_size, void* d_ws, size_t ws_size,
                              hipStream_t stream)
{
    const float* x  = (const float*)d_in[0];
    const float* Wq = (const float*)d_in[1];
    const float* bq = (const float*)d_in[2];
    const float* Wk = (const float*)d_in[3];
    const float* bk = (const float*)d_in[4];
    const float* Wv = (const float*)d_in[5];
    const float* bv = (const float*)d_in[6];
    const float* Wo = (const float*)d_in[7];
    const float* bo = (const float*)d_in[8];

    // workspace layout (~163 MB):
    unsigned short* xh = (unsigned short*)d_ws;                    // [16384][1024] bf16 hi (x, then att)
    unsigned short* xl = xh + (size_t)NROWS * DMODEL;              // lo
    unsigned short* wsp = xl + (size_t)NROWS * DMODEL;             // 8 x 1M bf16: q_h,q_l,k_h,k_l,v_h,v_l,o_h,o_l
    float* buf0 = (float*)(wsp + 8u * M1);                         // k, then q (fp32)
    float* kv   = buf0 + (size_t)NROWS * DMODEL;                   // [NBH][64][64]
    float* ksum = kv + NBH * HDIM * HDIM;                          // [NBH][64]
    float* kvp  = ksum + NBH * HDIM;                               // [SCHUNK][NBH][64][64]
    float* ksp  = kvp + (size_t)SCHUNK * NBH * HDIM * HDIM;        // [SCHUNK][NBH][64]
    float* vbuf = (float*)d_out;                                   // v lives in d_out (dead before final GEMM)

    const dim3 gg(256);   // (16384/256) x (1024/256) = 64 x 4, flat + XCD swizzle
    const int n4x = NROWS * DMODEL / 4;

    // convert weights + x to bf16 hi/lo
    split_w4<<<dim3(1024, 4), 256, 0, stream>>>(Wq, Wk, Wv, Wo, wsp);
    split_pair<<<4096, 256, 0, stream>>>(x, xh, xl, n4x);
    // k = elu(x@Wk^T + bk)+1 ; v = x@Wv^T + bv
    gemm_cp<1><<<gg, 512, 0, stream>>>(xh, xl, wsp + 2u * M1, wsp + 3u * M1, bk, buf0);
    gemm_cp<0><<<gg, 512, 0, stream>>>(xh, xl, wsp + 4u * M1, wsp + 5u * M1, bv, vbuf);
    // kv, ksum (deterministic split-K + reduce)
    kv_partial<<<dim3(NBH, SCHUNK), 512, 0, stream>>>(buf0, vbuf, kvp, ksp);
    kv_reduce<<<1024, 256, 0, stream>>>(kvp, ksp, kv, ksum);
    // q = elu(x@Wq^T + bq)+1   (overwrites k)
    gemm_cp<1><<<gg, 512, 0, stream>>>(xh, xl, wsp, wsp + M1, bq, buf0);
    // att = (q@kv)/(q@ksum + 1e-6), fused bf16 hi/lo split (x split is dead; reuse xh/xl)
    qkv_norm<<<dim3(SEQ / 64, NBATCH, NHEAD), 256, 0, stream>>>(buf0, kv, ksum, xh, xl);
    // out = att@Wo^T + bo  (overwrites v in d_out)
    gemm_cp<0><<<gg, 512, 0, stream>>>(xh, xl, wsp + 6u * M1, wsp + 7u * M1, bo, (float*)d_out);
}